// Round 6
// baseline (262.616 us; speedup 1.0000x reference)
//
#include <hip/hip_runtime.h>
#include <hip/hip_bf16.h>

#define B_ 4
#define L_ 1024
#define H_ 12
#define DK_ 64
#define FEA_ 768
#define MASKV (-32767.0f)

typedef __attribute__((ext_vector_type(8))) short bf16x8;
typedef __attribute__((ext_vector_type(4))) short s16x4;
typedef __attribute__((ext_vector_type(4))) float f32x4;
typedef unsigned int u32;

__device__ inline short f2bf(float x) {
  __hip_bfloat16 h = __float2bfloat16(x);   // HW cvt, RNE
  return __builtin_bit_cast(short, h);
}

// ---------------------------------------------------------------------------
// QKV projection: out[m][n] = sum_k X[m][k] * W[n][k] + b[n]
// M=4096, N=768, K=768. 128x128 tile, BK=64, 4 waves (2x2), bf16 MFMA.
// Double-buffered LDS, 1 barrier/k-step, global loads issued before compute.
// Q,K stored [b][h][l][d] bf16; V stored transposed [b][h][d][l] bf16.
// ---------------------------------------------------------------------------
__global__ __launch_bounds__(256) void k_proj(
    const float* __restrict__ qx, const float* __restrict__ kx,
    const float* __restrict__ vx,
    const float* __restrict__ Wq, const float* __restrict__ bq,
    const float* __restrict__ Wk, const float* __restrict__ bk,
    const float* __restrict__ Wv, const float* __restrict__ bv,
    unsigned short* __restrict__ Qb, unsigned short* __restrict__ Kb,
    unsigned short* __restrict__ Vt)
{
  __shared__ short lA[2][128 * 64];
  __shared__ short lB[2][128 * 64];

  const int which = blockIdx.z;
  const float* __restrict__ A    = (which == 0) ? qx : (which == 1) ? kx : vx;
  const float* __restrict__ W    = (which == 0) ? Wq : (which == 1) ? Wk : Wv;
  const float* __restrict__ bias = (which == 0) ? bq : (which == 1) ? bk : bv;

  const int tid = threadIdx.x;
  const int lane = tid & 63;
  const int wid = tid >> 6;
  const int wr = wid >> 1, wc = wid & 1;
  const int m0 = blockIdx.x * 128;
  const int n0 = blockIdx.y * 128;
  const int g = lane >> 4, qc = lane & 15;

  float4 rA[8], rB[8];

#define PROJ_LOAD(ktof)                                                        \
  {                                                                            \
    _Pragma("unroll")                                                          \
    for (int i_ = 0; i_ < 4; i_++) {                                           \
      int gg_ = i_ * 256 + tid;                                                \
      int row_ = gg_ >> 3, c_ = gg_ & 7;                                       \
      const float4* pa_ = (const float4*)(A + (size_t)(m0 + row_) * FEA_ + (ktof) + c_ * 8); \
      rA[i_ * 2] = pa_[0]; rA[i_ * 2 + 1] = pa_[1];                            \
      const float4* pb_ = (const float4*)(W + (size_t)(n0 + row_) * FEA_ + (ktof) + c_ * 8); \
      rB[i_ * 2] = pb_[0]; rB[i_ * 2 + 1] = pb_[1];                            \
    }                                                                          \
  }

#define PROJ_WRITE(buf)                                                        \
  {                                                                            \
    _Pragma("unroll")                                                          \
    for (int i_ = 0; i_ < 4; i_++) {                                           \
      int gg_ = i_ * 256 + tid;                                                \
      int row_ = gg_ >> 3, c_ = gg_ & 7;                                       \
      bf16x8 av_;                                                              \
      av_[0] = f2bf(rA[i_ * 2].x);     av_[1] = f2bf(rA[i_ * 2].y);            \
      av_[2] = f2bf(rA[i_ * 2].z);     av_[3] = f2bf(rA[i_ * 2].w);            \
      av_[4] = f2bf(rA[i_ * 2 + 1].x); av_[5] = f2bf(rA[i_ * 2 + 1].y);        \
      av_[6] = f2bf(rA[i_ * 2 + 1].z); av_[7] = f2bf(rA[i_ * 2 + 1].w);        \
      *(bf16x8*)&lA[buf][row_ * 64 + ((c_ ^ (row_ & 7)) << 3)] = av_;          \
      bf16x8 bw_;                                                              \
      bw_[0] = f2bf(rB[i_ * 2].x);     bw_[1] = f2bf(rB[i_ * 2].y);            \
      bw_[2] = f2bf(rB[i_ * 2].z);     bw_[3] = f2bf(rB[i_ * 2].w);            \
      bw_[4] = f2bf(rB[i_ * 2 + 1].x); bw_[5] = f2bf(rB[i_ * 2 + 1].y);        \
      bw_[6] = f2bf(rB[i_ * 2 + 1].z); bw_[7] = f2bf(rB[i_ * 2 + 1].w);        \
      *(bf16x8*)&lB[buf][row_ * 64 + ((c_ ^ (row_ & 7)) << 3)] = bw_;          \
    }                                                                          \
  }

  f32x4 acc[4][4];
#pragma unroll
  for (int i = 0; i < 4; i++)
#pragma unroll
    for (int j = 0; j < 4; j++) acc[i][j] = f32x4{0.f, 0.f, 0.f, 0.f};

  PROJ_LOAD(0);
  PROJ_WRITE(0);
  __syncthreads();

  for (int kt = 0; kt < 12; kt++) {
    const int cur = kt & 1, nxt = cur ^ 1;
    if (kt < 11) PROJ_LOAD((kt + 1) * 64);
#pragma unroll
    for (int s = 0; s < 2; s++) {
      bf16x8 af[4], bfr[4];
#pragma unroll
      for (int i = 0; i < 4; i++) {
        int ar = wr * 64 + i * 16 + qc;
        af[i] = *(const bf16x8*)&lA[cur][ar * 64 + (((s * 4 + g) ^ (ar & 7)) << 3)];
        int br = wc * 64 + i * 16 + qc;
        bfr[i] = *(const bf16x8*)&lB[cur][br * 64 + (((s * 4 + g) ^ (br & 7)) << 3)];
      }
#pragma unroll
      for (int i = 0; i < 4; i++)
#pragma unroll
        for (int j = 0; j < 4; j++)
          acc[i][j] = __builtin_amdgcn_mfma_f32_16x16x32_bf16(af[i], bfr[j], acc[i][j], 0, 0, 0);
    }
    if (kt < 11) PROJ_WRITE(nxt);
    __syncthreads();
  }

  const int cn0 = n0 + wc * 64;
  float bv4[4];
#pragma unroll
  for (int j = 0; j < 4; j++) bv4[j] = bias[cn0 + j * 16 + qc];

#pragma unroll
  for (int i = 0; i < 4; i++) {
    int m = m0 + wr * 64 + i * 16 + g * 4;
    int bb = m >> 10;
    int l = m & 1023;
#pragma unroll
    for (int j = 0; j < 4; j++) {
      int n = cn0 + j * 16 + qc;
      int hh = n >> 6, d = n & 63;
#pragma unroll
      for (int r = 0; r < 4; r++) {
        unsigned short v = (unsigned short)f2bf(acc[i][j][r] + bv4[j]);
        if (which == 2) {
          Vt[(((size_t)bb * H_ + hh) * DK_ + d) * L_ + (l + r)] = v;
        } else if (which == 0) {
          Qb[(((size_t)bb * H_ + hh) * L_ + (l + r)) * DK_ + d] = v;
        } else {
          Kb[(((size_t)bb * H_ + hh) * L_ + (l + r)) * DK_ + d] = v;
        }
      }
    }
  }
#undef PROJ_LOAD
#undef PROJ_WRITE
}

// ---------------------------------------------------------------------------
// Fused attention v6: R4 structure (4 waves, 40KB LDS, minimal traffic) +
// no-max softmax (scores bounded << 88, masked exp == 0 exactly) + DEPTH-2
// ps/mask register prefetch (named psn0/psn1 buffers; literal indices via
// 2-unrolled tile macro). Counted-vmcnt barrier keeps 24+ VMEM ops in flight
// per wave -> Little's-law BW up.
// ---------------------------------------------------------------------------
__global__ __launch_bounds__(256, 3) void k_attn(
    const unsigned short* __restrict__ Qb, const unsigned short* __restrict__ Kb,
    const unsigned short* __restrict__ Vt,
    const float* __restrict__ preScores, const int* __restrict__ maskPAD,
    float* __restrict__ scoresOut, unsigned short* __restrict__ zp)
{
  __shared__ short lK[2][64 * 64];
  __shared__ short lV[2][64 * 64];
  __shared__ short lP[4][16 * 64];

  const int tid = threadIdx.x, lane = tid & 63, wid = tid >> 6;
  const int qt = blockIdx.x, h = blockIdx.y, b = blockIdx.z;
  const int q0 = qt * 64;
  const int g = lane >> 4, qr = lane & 15;
  const int qrow = q0 + wid * 16 + qr;    // global q row in [0,1024)

  const size_t bh = (size_t)b * H_ + h;
  const unsigned short* __restrict__ Kbh = Kb + bh * L_ * DK_;
  const unsigned short* __restrict__ Vbh = Vt + bh * DK_ * L_;

  const int srow = lane >> 3;
  const int spos = lane & 7;

#define STAGE_KV(buf, kv0)                                                     \
  {                                                                            \
    _Pragma("unroll")                                                          \
    for (int i_ = 0; i_ < 2; i_++) {                                           \
      int r0_ = wid * 16 + i_ * 8;                                             \
      int row_ = r0_ + srow;                                                   \
      int cs_ = spos ^ (row_ & 7);                                             \
      __builtin_amdgcn_global_load_lds(                                        \
          (const __attribute__((address_space(1))) u32*)(Kbh +                 \
              (size_t)((kv0) + row_) * DK_ + cs_ * 8),                         \
          (__attribute__((address_space(3))) u32*)&lK[buf][r0_ * 64],          \
          16, 0, 0);                                                           \
      __builtin_amdgcn_global_load_lds(                                        \
          (const __attribute__((address_space(1))) u32*)(Vbh +                 \
              (size_t)row_ * L_ + (kv0) + cs_ * 8),                            \
          (__attribute__((address_space(3))) u32*)&lV[buf][r0_ * 64],          \
          16, 0, 0);                                                           \
    }                                                                          \
  }

  bf16x8 qf[2];
#pragma unroll
  for (int s = 0; s < 2; s++)
    qf[s] = *(const bf16x8*)(Qb + (bh * L_ + qrow) * DK_ + s * 32 + g * 8);

  f32x4 o[4];
#pragma unroll
  for (int i = 0; i < 4; i++) o[i] = f32x4{0.f, 0.f, 0.f, 0.f};
  float psum = 0.f;                       // per-lane partial sum (no-max)

  const size_t psBase = (bh * L_ + qrow) * L_;
  const size_t mkBase = ((size_t)b * L_ + qrow) * L_;

  // prologue: stage tile 0 (pinned oldest); prefetch ps/mask tiles 0 and 1
  STAGE_KV(0, 0);
  __builtin_amdgcn_sched_barrier(0);
  float4 psn0[4], psn1[4];
  int4 mkn0[4], mkn1[4];
#pragma unroll
  for (int i = 0; i < 4; i++) {
    psn0[i] = *(const float4*)(preScores + psBase + i * 16 + g * 4);
    mkn0[i] = *(const int4*)(maskPAD + mkBase + i * 16 + g * 4);
  }
#pragma unroll
  for (int i = 0; i < 4; i++) {
    psn1[i] = *(const float4*)(preScores + psBase + 64 + i * 16 + g * 4);
    mkn1[i] = *(const int4*)(maskPAD + mkBase + 64 + i * 16 + g * 4);
  }
  asm volatile("s_waitcnt vmcnt(16)" ::: "memory");
  __builtin_amdgcn_s_barrier();

  // One kv-tile. CUR/NXT are literal 0/1 (rule #20: no runtime-indexed
  // register arrays). Steady-state outstanding at the barrier:
  // pf(kt+1):8 + st(kt-1):4 + STAGE(kt+1):4 + pf(kt+2):8 + st(kt):4 = 28;
  // vmcnt(12) retires through STAGE(kt+1), leaves pf(kt+2)+st(kt).
#define TILE_BODY(CUR, NXT, KT)                                                \
  {                                                                            \
    const int kv0 = (KT) * 64;                                                 \
    if ((KT) < 15) STAGE_KV(NXT, kv0 + 64);                                    \
    __builtin_amdgcn_sched_barrier(0);                                         \
    float4 psc[4]; int4 mkc[4];                                                \
    _Pragma("unroll")                                                          \
    for (int i = 0; i < 4; i++) { psc[i] = psn##CUR[i]; mkc[i] = mkn##CUR[i]; }\
    if ((KT) < 14) {                                                           \
      _Pragma("unroll")                                                        \
      for (int i = 0; i < 4; i++) {                                            \
        psn##CUR[i] = *(const float4*)(preScores + psBase + kv0 + 128 + i * 16 + g * 4); \
        mkn##CUR[i] = *(const int4*)(maskPAD + mkBase + kv0 + 128 + i * 16 + g * 4);     \
      }                                                                        \
    }                                                                          \
    f32x4 st[4];                                                               \
    _Pragma("unroll")                                                          \
    for (int i = 0; i < 4; i++) st[i] = f32x4{0.f, 0.f, 0.f, 0.f};             \
    __builtin_amdgcn_s_setprio(1);                                             \
    _Pragma("unroll")                                                          \
    for (int s = 0; s < 2; s++) {                                              \
      _Pragma("unroll")                                                        \
      for (int i = 0; i < 4; i++) {                                            \
        int kr = i * 16 + qr;                                                  \
        bf16x8 kf = *(const bf16x8*)&lK[CUR][kr * 64 + (((s * 4 + g) ^ (kr & 7)) << 3)]; \
        st[i] = __builtin_amdgcn_mfma_f32_16x16x32_bf16(kf, qf[s], st[i], 0, 0, 0);      \
      }                                                                        \
    }                                                                          \
    __builtin_amdgcn_s_setprio(0);                                             \
    _Pragma("unroll")                                                          \
    for (int i = 0; i < 4; i++) {                                              \
      int ko = i * 16 + g * 4;                                                 \
      float4 sv;                                                               \
      sv.x = (mkc[i].x == 0) ? MASKV : st[i][0] * 0.125f + psc[i].x;           \
      sv.y = (mkc[i].y == 0) ? MASKV : st[i][1] * 0.125f + psc[i].y;           \
      sv.z = (mkc[i].z == 0) ? MASKV : st[i][2] * 0.125f + psc[i].z;           \
      sv.w = (mkc[i].w == 0) ? MASKV : st[i][3] * 0.125f + psc[i].w;           \
      *(float4*)(scoresOut + psBase + kv0 + ko) = sv;                          \
      float p0 = __expf(sv.x);                                                 \
      float p1 = __expf(sv.y);                                                 \
      float p2 = __expf(sv.z);                                                 \
      float p3 = __expf(sv.w);                                                 \
      psum += (p0 + p1) + (p2 + p3);                                           \
      s16x4 pw = {f2bf(p0), f2bf(p1), f2bf(p2), f2bf(p3)};                     \
      int c = i * 2 + (g >> 1);                                                \
      *(s16x4*)&lP[wid][qr * 64 + ((c ^ (qr & 7)) << 3) + ((g & 1) << 2)] = pw;\
    }                                                                          \
    __builtin_amdgcn_s_setprio(1);                                             \
    _Pragma("unroll")                                                          \
    for (int s = 0; s < 2; s++) {                                              \
      bf16x8 pf = *(const bf16x8*)&lP[wid][qr * 64 + (((s * 4 + g) ^ (qr & 7)) << 3)];   \
      _Pragma("unroll")                                                        \
      for (int i = 0; i < 4; i++) {                                            \
        int vr = i * 16 + qr;                                                  \
        bf16x8 vf = *(const bf16x8*)&lV[CUR][vr * 64 + (((s * 4 + g) ^ (vr & 7)) << 3)]; \
        o[i] = __builtin_amdgcn_mfma_f32_16x16x32_bf16(vf, pf, o[i], 0, 0, 0); \
      }                                                                        \
    }                                                                          \
    __builtin_amdgcn_s_setprio(0);                                             \
    asm volatile("s_waitcnt vmcnt(12)" ::: "memory");                          \
    __builtin_amdgcn_s_barrier();                                              \
  }

  for (int kt = 0; kt < 16; kt += 2) {
    TILE_BODY(0, 1, kt);
    TILE_BODY(1, 0, kt + 1);
  }

  // final row-sum reduce (2 shuffles) + normalize + write z_pre
  psum += __shfl_xor(psum, 16);
  psum += __shfl_xor(psum, 32);
  float inv = 1.f / psum;
  size_t zr = ((size_t)b * L_ + qrow) * FEA_ + (size_t)h * DK_;
#pragma unroll
  for (int i = 0; i < 4; i++) {
    s16x4 zw = {f2bf(o[i][0] * inv), f2bf(o[i][1] * inv),
                f2bf(o[i][2] * inv), f2bf(o[i][3] * inv)};
    *(s16x4*)((unsigned short*)zp + zr + i * 16 + g * 4) = zw;
  }
#undef STAGE_KV
#undef TILE_BODY
}

// ---------------------------------------------------------------------------
// Output projection: out[m][n] = sum_k zp[m][k] * Wo[n][k] + bo[n], fp32 out.
// Double-buffered LDS, 1 barrier/k-step, loads issued before compute.
// ---------------------------------------------------------------------------
__global__ __launch_bounds__(256) void k_oproj(
    const unsigned short* __restrict__ zp,
    const float* __restrict__ Wo, const float* __restrict__ bo,
    float* __restrict__ out)
{
  __shared__ short lA[2][128 * 64];
  __shared__ short lB[2][128 * 64];

  const int tid = threadIdx.x;
  const int lane = tid & 63;
  const int wid = tid >> 6;
  const int wr = wid >> 1, wc = wid & 1;
  const int m0 = blockIdx.x * 128;
  const int n0 = blockIdx.y * 128;
  const int g = lane >> 4, qc = lane & 15;

  bf16x8 rA[4];
  float4 rB[8];

#define OP_LOAD(ktof)                                                          \
  {                                                                            \
    _Pragma("unroll")                                                          \
    for (int i_ = 0; i_ < 4; i_++) {                                           \
      int gg_ = i_ * 256 + tid;                                                \
      int row_ = gg_ >> 3, c_ = gg_ & 7;                                       \
      rA[i_] = *(const bf16x8*)(zp + (size_t)(m0 + row_) * FEA_ + (ktof) + c_ * 8); \
      const float4* pb_ = (const float4*)(Wo + (size_t)(n0 + row_) * FEA_ + (ktof) + c_ * 8); \
      rB[i_ * 2] = pb_[0]; rB[i_ * 2 + 1] = pb_[1];                            \
    }                                                                          \
  }

#define OP_WRITE(buf)                                                          \
  {                                                                            \
    _Pragma("unroll")                                                          \
    for (int i_ = 0; i_ < 4; i_++) {                                           \
      int gg_ = i_ * 256 + tid;                                                \
      int row_ = gg_ >> 3, c_ = gg_ & 7;                                       \
      *(bf16x8*)&lA[buf][row_ * 64 + ((c_ ^ (row_ & 7)) << 3)] = rA[i_];       \
      bf16x8 bw_;                                                              \
      bw_[0] = f2bf(rB[i_ * 2].x);     bw_[1] = f2bf(rB[i_ * 2].y);            \
      bw_[2] = f2bf(rB[i_ * 2].z);     bw_[3] = f2bf(rB[i_ * 2].w);            \
      bw_[4] = f2bf(rB[i_ * 2 + 1].x); bw_[5] = f2bf(rB[i_ * 2 + 1].y);        \
      bw_[6] = f2bf(rB[i_ * 2 + 1].z); bw_[7] = f2bf(rB[i_ * 2 + 1].w);        \
      *(bf16x8*)&lB[buf][row_ * 64 + ((c_ ^ (row_ & 7)) << 3)] = bw_;          \
    }                                                                          \
  }

  f32x4 acc[4][4];
#pragma unroll
  for (int i = 0; i < 4; i++)
#pragma unroll
    for (int j = 0; j < 4; j++) acc[i][j] = f32x4{0.f, 0.f, 0.f, 0.f};

  OP_LOAD(0);
  OP_WRITE(0);
  __syncthreads();

  for (int kt = 0; kt < 12; kt++) {
    const int cur = kt & 1, nxt = cur ^ 1;
    if (kt < 11) OP_LOAD((kt + 1) * 64);
#pragma unroll
    for (int s = 0; s < 2; s++) {
      bf16x8 af[4], bfr[4];
#pragma unroll
      for (int i = 0; i < 4; i++) {
        int ar = wr * 64 + i * 16 + qc;
        af[i] = *(const bf16x8*)&lA[cur][ar * 64 + (((s * 4 + g) ^ (ar & 7)) << 3)];
        int br = wc * 64 + i * 16 + qc;
        bfr[i] = *(const bf16x8*)&lB[cur][br * 64 + (((s * 4 + g) ^ (br & 7)) << 3)];
      }
#pragma unroll
      for (int i = 0; i < 4; i++)
#pragma unroll
        for (int j = 0; j < 4; j++)
          acc[i][j] = __builtin_amdgcn_mfma_f32_16x16x32_bf16(af[i], bfr[j], acc[i][j], 0, 0, 0);
    }
    if (kt < 11) OP_WRITE(nxt);
    __syncthreads();
  }

  const int cn0 = n0 + wc * 64;
  float bv4[4];
#pragma unroll
  for (int j = 0; j < 4; j++) bv4[j] = bo[cn0 + j * 16 + qc];

#pragma unroll
  for (int i = 0; i < 4; i++) {
    int m = m0 + wr * 64 + i * 16 + g * 4;
#pragma unroll
    for (int j = 0; j < 4; j++) {
      int n = cn0 + j * 16 + qc;
#pragma unroll
      for (int r = 0; r < 4; r++) {
        out[(size_t)(m + r) * FEA_ + n] = acc[i][j][r] + bv4[j];
      }
    }
  }
#undef OP_LOAD
#undef OP_WRITE
}

extern "C" void kernel_launch(void* const* d_in, const int* in_sizes, int n_in,
                              void* d_out, int out_size, void* d_ws, size_t ws_size,
                              hipStream_t stream) {
  const float* qx = (const float*)d_in[0];
  const float* kx = (const float*)d_in[1];
  const float* vx = (const float*)d_in[2];
  const float* preScores = (const float*)d_in[3];
  const int* maskPAD = (const int*)d_in[4];
  const float* Wq = (const float*)d_in[5];
  const float* bq = (const float*)d_in[6];
  const float* Wk = (const float*)d_in[7];
  const float* bk = (const float*)d_in[8];
  const float* Wv = (const float*)d_in[9];
  const float* bv = (const float*)d_in[10];
  const float* Wo = (const float*)d_in[11];
  const float* bo = (const float*)d_in[12];

  float* z_out = (float*)d_out;
  float* scores_out = z_out + (size_t)B_ * L_ * FEA_;

  unsigned short* Qb = (unsigned short*)d_ws;
  unsigned short* Kb = Qb + (size_t)B_ * H_ * L_ * DK_;
  unsigned short* Vt = Kb + (size_t)B_ * H_ * L_ * DK_;
  unsigned short* zp = Vt + (size_t)B_ * H_ * L_ * DK_;

  k_proj<<<dim3(32, 6, 3), 256, 0, stream>>>(qx, kx, vx, Wq, bq, Wk, bk, Wv, bv,
                                             Qb, Kb, Vt);
  k_attn<<<dim3(L_ / 64, H_, B_), 256, 0, stream>>>(Qb, Kb, Vt, preScores,
                                                    maskPAD, scores_out, zp);
  k_oproj<<<dim3(32, 6, 1), 256, 0, stream>>>(zp, Wo, bo, z_out);
}

// Round 7
// 210.647 us; speedup vs baseline: 1.2467x; 1.2467x over previous
//
#include <hip/hip_runtime.h>
#include <hip/hip_bf16.h>

#define B_ 4
#define L_ 1024
#define H_ 12
#define DK_ 64
#define FEA_ 768
#define MASKV (-32767.0f)

typedef __attribute__((ext_vector_type(8))) short bf16x8;
typedef __attribute__((ext_vector_type(4))) short s16x4;
typedef __attribute__((ext_vector_type(4))) float f32x4;
typedef unsigned int u32;

__device__ inline short f2bf(float x) {
  __hip_bfloat16 h = __float2bfloat16(x);   // HW cvt, RNE
  return __builtin_bit_cast(short, h);
}

// ---------------------------------------------------------------------------
// QKV projection: out[m][n] = sum_k X[m][k] * W[n][k] + b[n]
// M=4096, N=768, K=768. 128x128 tile, BK=64, 4 waves (2x2), bf16 MFMA.
// Double-buffered LDS, 1 barrier/k-step, global loads issued before compute.
// Q,K stored [b][h][l][d] bf16; V stored transposed [b][h][d][l] bf16.
// ---------------------------------------------------------------------------
__global__ __launch_bounds__(256) void k_proj(
    const float* __restrict__ qx, const float* __restrict__ kx,
    const float* __restrict__ vx,
    const float* __restrict__ Wq, const float* __restrict__ bq,
    const float* __restrict__ Wk, const float* __restrict__ bk,
    const float* __restrict__ Wv, const float* __restrict__ bv,
    unsigned short* __restrict__ Qb, unsigned short* __restrict__ Kb,
    unsigned short* __restrict__ Vt)
{
  __shared__ short lA[2][128 * 64];
  __shared__ short lB[2][128 * 64];

  const int which = blockIdx.z;
  const float* __restrict__ A    = (which == 0) ? qx : (which == 1) ? kx : vx;
  const float* __restrict__ W    = (which == 0) ? Wq : (which == 1) ? Wk : Wv;
  const float* __restrict__ bias = (which == 0) ? bq : (which == 1) ? bk : bv;

  const int tid = threadIdx.x;
  const int lane = tid & 63;
  const int wid = tid >> 6;
  const int wr = wid >> 1, wc = wid & 1;
  const int m0 = blockIdx.x * 128;
  const int n0 = blockIdx.y * 128;
  const int g = lane >> 4, qc = lane & 15;

  float4 rA[8], rB[8];

#define PROJ_LOAD(ktof)                                                        \
  {                                                                            \
    _Pragma("unroll")                                                          \
    for (int i_ = 0; i_ < 4; i_++) {                                           \
      int gg_ = i_ * 256 + tid;                                                \
      int row_ = gg_ >> 3, c_ = gg_ & 7;                                       \
      const float4* pa_ = (const float4*)(A + (size_t)(m0 + row_) * FEA_ + (ktof) + c_ * 8); \
      rA[i_ * 2] = pa_[0]; rA[i_ * 2 + 1] = pa_[1];                            \
      const float4* pb_ = (const float4*)(W + (size_t)(n0 + row_) * FEA_ + (ktof) + c_ * 8); \
      rB[i_ * 2] = pb_[0]; rB[i_ * 2 + 1] = pb_[1];                            \
    }                                                                          \
  }

#define PROJ_WRITE(buf)                                                        \
  {                                                                            \
    _Pragma("unroll")                                                          \
    for (int i_ = 0; i_ < 4; i_++) {                                           \
      int gg_ = i_ * 256 + tid;                                                \
      int row_ = gg_ >> 3, c_ = gg_ & 7;                                       \
      bf16x8 av_;                                                              \
      av_[0] = f2bf(rA[i_ * 2].x);     av_[1] = f2bf(rA[i_ * 2].y);            \
      av_[2] = f2bf(rA[i_ * 2].z);     av_[3] = f2bf(rA[i_ * 2].w);            \
      av_[4] = f2bf(rA[i_ * 2 + 1].x); av_[5] = f2bf(rA[i_ * 2 + 1].y);        \
      av_[6] = f2bf(rA[i_ * 2 + 1].z); av_[7] = f2bf(rA[i_ * 2 + 1].w);        \
      *(bf16x8*)&lA[buf][row_ * 64 + ((c_ ^ (row_ & 7)) << 3)] = av_;          \
      bf16x8 bw_;                                                              \
      bw_[0] = f2bf(rB[i_ * 2].x);     bw_[1] = f2bf(rB[i_ * 2].y);            \
      bw_[2] = f2bf(rB[i_ * 2].z);     bw_[3] = f2bf(rB[i_ * 2].w);            \
      bw_[4] = f2bf(rB[i_ * 2 + 1].x); bw_[5] = f2bf(rB[i_ * 2 + 1].y);        \
      bw_[6] = f2bf(rB[i_ * 2 + 1].z); bw_[7] = f2bf(rB[i_ * 2 + 1].w);        \
      *(bf16x8*)&lB[buf][row_ * 64 + ((c_ ^ (row_ & 7)) << 3)] = bw_;          \
    }                                                                          \
  }

  f32x4 acc[4][4];
#pragma unroll
  for (int i = 0; i < 4; i++)
#pragma unroll
    for (int j = 0; j < 4; j++) acc[i][j] = f32x4{0.f, 0.f, 0.f, 0.f};

  PROJ_LOAD(0);
  PROJ_WRITE(0);
  __syncthreads();

  for (int kt = 0; kt < 12; kt++) {
    const int cur = kt & 1, nxt = cur ^ 1;
    if (kt < 11) PROJ_LOAD((kt + 1) * 64);
#pragma unroll
    for (int s = 0; s < 2; s++) {
      bf16x8 af[4], bfr[4];
#pragma unroll
      for (int i = 0; i < 4; i++) {
        int ar = wr * 64 + i * 16 + qc;
        af[i] = *(const bf16x8*)&lA[cur][ar * 64 + (((s * 4 + g) ^ (ar & 7)) << 3)];
        int br = wc * 64 + i * 16 + qc;
        bfr[i] = *(const bf16x8*)&lB[cur][br * 64 + (((s * 4 + g) ^ (br & 7)) << 3)];
      }
#pragma unroll
      for (int i = 0; i < 4; i++)
#pragma unroll
        for (int j = 0; j < 4; j++)
          acc[i][j] = __builtin_amdgcn_mfma_f32_16x16x32_bf16(af[i], bfr[j], acc[i][j], 0, 0, 0);
    }
    if (kt < 11) PROJ_WRITE(nxt);
    __syncthreads();
  }

  const int cn0 = n0 + wc * 64;
  float bv4[4];
#pragma unroll
  for (int j = 0; j < 4; j++) bv4[j] = bias[cn0 + j * 16 + qc];

#pragma unroll
  for (int i = 0; i < 4; i++) {
    int m = m0 + wr * 64 + i * 16 + g * 4;
    int bb = m >> 10;
    int l = m & 1023;
#pragma unroll
    for (int j = 0; j < 4; j++) {
      int n = cn0 + j * 16 + qc;
      int hh = n >> 6, d = n & 63;
#pragma unroll
      for (int r = 0; r < 4; r++) {
        unsigned short v = (unsigned short)f2bf(acc[i][j][r] + bv4[j]);
        if (which == 2) {
          Vt[(((size_t)bb * H_ + hh) * DK_ + d) * L_ + (l + r)] = v;
        } else if (which == 0) {
          Qb[(((size_t)bb * H_ + hh) * L_ + (l + r)) * DK_ + d] = v;
        } else {
          Kb[(((size_t)bb * H_ + hh) * L_ + (l + r)) * DK_ + d] = v;
        }
      }
    }
  }
#undef PROJ_LOAD
#undef PROJ_WRITE
}

// ---------------------------------------------------------------------------
// Fused attention v7: R4 memory schedule (depth-1 prefetch, vmcnt(12) counted
// barrier, 40KB LDS, 4 waves) + no-max softmax (register-only) + NON-TEMPORAL
// scores stores (write-once stream; keep L3 for mask/preScores) + XCD-aware
// block mapping: block i -> XCD i&7; each XCD owns 6 (b,h) pairs x 16 q-tiles
// so K/V (512KB each, 3MB total) stay L2-resident per XCD.
// ---------------------------------------------------------------------------
__global__ __launch_bounds__(256, 3) void k_attn(
    const unsigned short* __restrict__ Qb, const unsigned short* __restrict__ Kb,
    const unsigned short* __restrict__ Vt,
    const float* __restrict__ preScores, const int* __restrict__ maskPAD,
    float* __restrict__ scoresOut, unsigned short* __restrict__ zp)
{
  __shared__ short lK[2][64 * 64];
  __shared__ short lV[2][64 * 64];
  __shared__ short lP[4][16 * 64];

  const int tid = threadIdx.x, lane = tid & 63, wid = tid >> 6;
  // XCD-aware decode: consecutive blockIdx round-robin across 8 XCDs.
  // XCD x gets bh in [x*6, x*6+6), all 16 q-tiles each. 768 = 8*6*16 exact.
  const int bi = blockIdx.x;
  const int slot = bi >> 3;                    // 0..95 within XCD
  const int bh_i = (bi & 7) * 6 + (slot >> 4); // 0..47
  const int qt = slot & 15;
  const int b = bh_i / H_;
  const int h = bh_i % H_;
  const int q0 = qt * 64;
  const int g = lane >> 4, qr = lane & 15;
  const int qrow = q0 + wid * 16 + qr;    // global q row in [0,1024)

  const size_t bh = (size_t)b * H_ + h;
  const unsigned short* __restrict__ Kbh = Kb + bh * L_ * DK_;
  const unsigned short* __restrict__ Vbh = Vt + bh * DK_ * L_;

  const int srow = lane >> 3;
  const int spos = lane & 7;

#define STAGE_KV(buf, kv0)                                                     \
  {                                                                            \
    _Pragma("unroll")                                                          \
    for (int i_ = 0; i_ < 2; i_++) {                                           \
      int r0_ = wid * 16 + i_ * 8;                                             \
      int row_ = r0_ + srow;                                                   \
      int cs_ = spos ^ (row_ & 7);                                             \
      __builtin_amdgcn_global_load_lds(                                        \
          (const __attribute__((address_space(1))) u32*)(Kbh +                 \
              (size_t)((kv0) + row_) * DK_ + cs_ * 8),                         \
          (__attribute__((address_space(3))) u32*)&lK[buf][r0_ * 64],          \
          16, 0, 0);                                                           \
      __builtin_amdgcn_global_load_lds(                                        \
          (const __attribute__((address_space(1))) u32*)(Vbh +                 \
              (size_t)row_ * L_ + (kv0) + cs_ * 8),                            \
          (__attribute__((address_space(3))) u32*)&lV[buf][r0_ * 64],          \
          16, 0, 0);                                                           \
    }                                                                          \
  }

  bf16x8 qf[2];
#pragma unroll
  for (int s = 0; s < 2; s++)
    qf[s] = *(const bf16x8*)(Qb + (bh * L_ + qrow) * DK_ + s * 32 + g * 8);

  f32x4 o[4];
#pragma unroll
  for (int i = 0; i < 4; i++) o[i] = f32x4{0.f, 0.f, 0.f, 0.f};
  float psum = 0.f;                       // per-lane partial sum (no-max)

  const size_t psBase = (bh * L_ + qrow) * L_;
  const size_t mkBase = ((size_t)b * L_ + qrow) * L_;

  // prologue: stage tile 0 (pinned oldest), prefetch ps/mask tile 0
  STAGE_KV(0, 0);
  __builtin_amdgcn_sched_barrier(0);
  float4 psn[4];
  int4 mkn[4];
#pragma unroll
  for (int i = 0; i < 4; i++) {
    psn[i] = *(const float4*)(preScores + psBase + i * 16 + g * 4);
    mkn[i] = *(const int4*)(maskPAD + mkBase + i * 16 + g * 4);
  }
  asm volatile("s_waitcnt vmcnt(8)" ::: "memory");
  __builtin_amdgcn_s_barrier();

  for (int kt = 0; kt < 16; kt++) {
    const int kv0 = kt * 64;
    const int cur = kt & 1, nxt = cur ^ 1;

    // issue next tile staging first; pin as oldest outstanding vmem
    if (kt < 15) {
      STAGE_KV(nxt, kv0 + 64);
    }
    __builtin_amdgcn_sched_barrier(0);

    // rotate ps/mask prefetch (depth-1, R4-proven traffic-minimal)
    float4 psc[4]; int4 mkc[4];
#pragma unroll
    for (int i = 0; i < 4; i++) { psc[i] = psn[i]; mkc[i] = mkn[i]; }
    if (kt < 15) {
#pragma unroll
      for (int i = 0; i < 4; i++) {
        psn[i] = *(const float4*)(preScores + psBase + kv0 + 64 + i * 16 + g * 4);
        mkn[i] = *(const int4*)(maskPAD + mkBase + kv0 + 64 + i * 16 + g * 4);
      }
    }

    // S^T = K . Q^T from LDS
    f32x4 st[4];
#pragma unroll
    for (int i = 0; i < 4; i++) st[i] = f32x4{0.f, 0.f, 0.f, 0.f};
    __builtin_amdgcn_s_setprio(1);
#pragma unroll
    for (int s = 0; s < 2; s++) {
#pragma unroll
      for (int i = 0; i < 4; i++) {
        int kr = i * 16 + qr;
        bf16x8 kf = *(const bf16x8*)&lK[cur][kr * 64 + (((s * 4 + g) ^ (kr & 7)) << 3)];
        st[i] = __builtin_amdgcn_mfma_f32_16x16x32_bf16(kf, qf[s], st[i], 0, 0, 0);
      }
    }
    __builtin_amdgcn_s_setprio(0);

    // scale + preScores + mask; non-temporal scores store; exp (no max);
    // pack P to wave-private LDS. No cross-lane ops in the loop.
#pragma unroll
    for (int i = 0; i < 4; i++) {
      int ko = i * 16 + g * 4;
      f32x4 sv;
      sv[0] = (mkc[i].x == 0) ? MASKV : st[i][0] * 0.125f + psc[i].x;
      sv[1] = (mkc[i].y == 0) ? MASKV : st[i][1] * 0.125f + psc[i].y;
      sv[2] = (mkc[i].z == 0) ? MASKV : st[i][2] * 0.125f + psc[i].z;
      sv[3] = (mkc[i].w == 0) ? MASKV : st[i][3] * 0.125f + psc[i].w;
      __builtin_nontemporal_store(sv, (f32x4*)(scoresOut + psBase + kv0 + ko));
      float p0 = __expf(sv[0]);
      float p1 = __expf(sv[1]);
      float p2 = __expf(sv[2]);
      float p3 = __expf(sv[3]);
      psum += (p0 + p1) + (p2 + p3);
      s16x4 pw = {f2bf(p0), f2bf(p1), f2bf(p2), f2bf(p3)};
      int c = i * 2 + (g >> 1);
      *(s16x4*)&lP[wid][qr * 64 + ((c ^ (qr & 7)) << 3) + ((g & 1) << 2)] = pw;
    }

    // O^T += Vt_strip . P^T from LDS
    __builtin_amdgcn_s_setprio(1);
#pragma unroll
    for (int s = 0; s < 2; s++) {
      bf16x8 pf = *(const bf16x8*)&lP[wid][qr * 64 + (((s * 4 + g) ^ (qr & 7)) << 3)];
#pragma unroll
      for (int i = 0; i < 4; i++) {
        int vr = i * 16 + qr;
        bf16x8 vf = *(const bf16x8*)&lV[cur][vr * 64 + (((s * 4 + g) ^ (vr & 7)) << 3)];
        o[i] = __builtin_amdgcn_mfma_f32_16x16x32_bf16(vf, pf, o[i], 0, 0, 0);
      }
    }
    __builtin_amdgcn_s_setprio(0);

    // counted barrier: wait only the 4 staging loads (oldest); scores stores
    // (4) and ps/mask prefetch (8) stay in flight.
    asm volatile("s_waitcnt vmcnt(12)" ::: "memory");
    __builtin_amdgcn_s_barrier();
  }

  // final row-sum reduce (2 shuffles) + normalize + write z_pre
  psum += __shfl_xor(psum, 16);
  psum += __shfl_xor(psum, 32);
  float inv = 1.f / psum;
  size_t zr = ((size_t)b * L_ + qrow) * FEA_ + (size_t)h * DK_;
#pragma unroll
  for (int i = 0; i < 4; i++) {
    s16x4 zw = {f2bf(o[i][0] * inv), f2bf(o[i][1] * inv),
                f2bf(o[i][2] * inv), f2bf(o[i][3] * inv)};
    *(s16x4*)((unsigned short*)zp + zr + i * 16 + g * 4) = zw;
  }
#undef STAGE_KV
}

// ---------------------------------------------------------------------------
// Output projection: out[m][n] = sum_k zp[m][k] * Wo[n][k] + bo[n], fp32 out.
// Double-buffered LDS, 1 barrier/k-step; non-temporal final store.
// ---------------------------------------------------------------------------
__global__ __launch_bounds__(256) void k_oproj(
    const unsigned short* __restrict__ zp,
    const float* __restrict__ Wo, const float* __restrict__ bo,
    float* __restrict__ out)
{
  __shared__ short lA[2][128 * 64];
  __shared__ short lB[2][128 * 64];

  const int tid = threadIdx.x;
  const int lane = tid & 63;
  const int wid = tid >> 6;
  const int wr = wid >> 1, wc = wid & 1;
  const int m0 = blockIdx.x * 128;
  const int n0 = blockIdx.y * 128;
  const int g = lane >> 4, qc = lane & 15;

  bf16x8 rA[4];
  float4 rB[8];

#define OP_LOAD(ktof)                                                          \
  {                                                                            \
    _Pragma("unroll")                                                          \
    for (int i_ = 0; i_ < 4; i_++) {                                           \
      int gg_ = i_ * 256 + tid;                                                \
      int row_ = gg_ >> 3, c_ = gg_ & 7;                                       \
      rA[i_] = *(const bf16x8*)(zp + (size_t)(m0 + row_) * FEA_ + (ktof) + c_ * 8); \
      const float4* pb_ = (const float4*)(Wo + (size_t)(n0 + row_) * FEA_ + (ktof) + c_ * 8); \
      rB[i_ * 2] = pb_[0]; rB[i_ * 2 + 1] = pb_[1];                            \
    }                                                                          \
  }

#define OP_WRITE(buf)                                                          \
  {                                                                            \
    _Pragma("unroll")                                                          \
    for (int i_ = 0; i_ < 4; i_++) {                                           \
      int gg_ = i_ * 256 + tid;                                                \
      int row_ = gg_ >> 3, c_ = gg_ & 7;                                       \
      *(bf16x8*)&lA[buf][row_ * 64 + ((c_ ^ (row_ & 7)) << 3)] = rA[i_];       \
      bf16x8 bw_;                                                              \
      bw_[0] = f2bf(rB[i_ * 2].x);     bw_[1] = f2bf(rB[i_ * 2].y);            \
      bw_[2] = f2bf(rB[i_ * 2].z);     bw_[3] = f2bf(rB[i_ * 2].w);            \
      bw_[4] = f2bf(rB[i_ * 2 + 1].x); bw_[5] = f2bf(rB[i_ * 2 + 1].y);        \
      bw_[6] = f2bf(rB[i_ * 2 + 1].z); bw_[7] = f2bf(rB[i_ * 2 + 1].w);        \
      *(bf16x8*)&lB[buf][row_ * 64 + ((c_ ^ (row_ & 7)) << 3)] = bw_;          \
    }                                                                          \
  }

  f32x4 acc[4][4];
#pragma unroll
  for (int i = 0; i < 4; i++)
#pragma unroll
    for (int j = 0; j < 4; j++) acc[i][j] = f32x4{0.f, 0.f, 0.f, 0.f};

  OP_LOAD(0);
  OP_WRITE(0);
  __syncthreads();

  for (int kt = 0; kt < 12; kt++) {
    const int cur = kt & 1, nxt = cur ^ 1;
    if (kt < 11) OP_LOAD((kt + 1) * 64);
#pragma unroll
    for (int s = 0; s < 2; s++) {
      bf16x8 af[4], bfr[4];
#pragma unroll
      for (int i = 0; i < 4; i++) {
        int ar = wr * 64 + i * 16 + qc;
        af[i] = *(const bf16x8*)&lA[cur][ar * 64 + (((s * 4 + g) ^ (ar & 7)) << 3)];
        int br = wc * 64 + i * 16 + qc;
        bfr[i] = *(const bf16x8*)&lB[cur][br * 64 + (((s * 4 + g) ^ (br & 7)) << 3)];
      }
#pragma unroll
      for (int i = 0; i < 4; i++)
#pragma unroll
        for (int j = 0; j < 4; j++)
          acc[i][j] = __builtin_amdgcn_mfma_f32_16x16x32_bf16(af[i], bfr[j], acc[i][j], 0, 0, 0);
    }
    if (kt < 11) OP_WRITE(nxt);
    __syncthreads();
  }

  const int cn0 = n0 + wc * 64;
  float bv4[4];
#pragma unroll
  for (int j = 0; j < 4; j++) bv4[j] = bo[cn0 + j * 16 + qc];

#pragma unroll
  for (int i = 0; i < 4; i++) {
    int m = m0 + wr * 64 + i * 16 + g * 4;
#pragma unroll
    for (int j = 0; j < 4; j++) {
      int n = cn0 + j * 16 + qc;
#pragma unroll
      for (int r = 0; r < 4; r++) {
        __builtin_nontemporal_store(acc[i][j][r] + bv4[j],
                                    out + (size_t)(m + r) * FEA_ + n);
      }
    }
  }
#undef OP_LOAD
#undef OP_WRITE
}

extern "C" void kernel_launch(void* const* d_in, const int* in_sizes, int n_in,
                              void* d_out, int out_size, void* d_ws, size_t ws_size,
                              hipStream_t stream) {
  const float* qx = (const float*)d_in[0];
  const float* kx = (const float*)d_in[1];
  const float* vx = (const float*)d_in[2];
  const float* preScores = (const float*)d_in[3];
  const int* maskPAD = (const int*)d_in[4];
  const float* Wq = (const float*)d_in[5];
  const float* bq = (const float*)d_in[6];
  const float* Wk = (const float*)d_in[7];
  const float* bk = (const float*)d_in[8];
  const float* Wv = (const float*)d_in[9];
  const float* bv = (const float*)d_in[10];
  const float* Wo = (const float*)d_in[11];
  const float* bo = (const float*)d_in[12];

  float* z_out = (float*)d_out;
  float* scores_out = z_out + (size_t)B_ * L_ * FEA_;

  unsigned short* Qb = (unsigned short*)d_ws;
  unsigned short* Kb = Qb + (size_t)B_ * H_ * L_ * DK_;
  unsigned short* Vt = Kb + (size_t)B_ * H_ * L_ * DK_;
  unsigned short* zp = Vt + (size_t)B_ * H_ * L_ * DK_;

  k_proj<<<dim3(32, 6, 3), 256, 0, stream>>>(qx, kx, vx, Wq, bq, Wk, bk, Wv, bv,
                                             Qb, Kb, Vt);
  k_attn<<<dim3(8 * 6 * 16, 1, 1), 256, 0, stream>>>(Qb, Kb, Vt, preScores,
                                                     maskPAD, scores_out, zp);
  k_oproj<<<dim3(32, 6, 1), 256, 0, stream>>>(zp, Wo, bo, z_out);
}

// Round 8
// 201.754 us; speedup vs baseline: 1.3017x; 1.0441x over previous
//
#include <hip/hip_runtime.h>
#include <hip/hip_bf16.h>

#define B_ 4
#define L_ 1024
#define H_ 12
#define DK_ 64
#define FEA_ 768
#define MASKV (-32767.0f)

typedef __attribute__((ext_vector_type(8))) short bf16x8;
typedef __attribute__((ext_vector_type(4))) short s16x4;
typedef __attribute__((ext_vector_type(4))) float f32x4;
typedef unsigned int u32;

__device__ inline short f2bf(float x) {
  __hip_bfloat16 h = __float2bfloat16(x);   // HW cvt, RNE
  return __builtin_bit_cast(short, h);
}

// ---------------------------------------------------------------------------
// QKV projection: out[m][n] = sum_k X[m][k] * W[n][k] + b[n]
// M=4096, N=768, K=768. 128x128 tile, BK=64, 4 waves (2x2), bf16 MFMA.
// Double-buffered LDS, 1 barrier/k-step, global loads issued before compute.
// Q,K stored [b][h][l][d] bf16; V stored transposed [b][h][d][l] bf16.
// ---------------------------------------------------------------------------
__global__ __launch_bounds__(256) void k_proj(
    const float* __restrict__ qx, const float* __restrict__ kx,
    const float* __restrict__ vx,
    const float* __restrict__ Wq, const float* __restrict__ bq,
    const float* __restrict__ Wk, const float* __restrict__ bk,
    const float* __restrict__ Wv, const float* __restrict__ bv,
    unsigned short* __restrict__ Qb, unsigned short* __restrict__ Kb,
    unsigned short* __restrict__ Vt)
{
  __shared__ short lA[2][128 * 64];
  __shared__ short lB[2][128 * 64];

  const int which = blockIdx.z;
  const float* __restrict__ A    = (which == 0) ? qx : (which == 1) ? kx : vx;
  const float* __restrict__ W    = (which == 0) ? Wq : (which == 1) ? Wk : Wv;
  const float* __restrict__ bias = (which == 0) ? bq : (which == 1) ? bk : bv;

  const int tid = threadIdx.x;
  const int lane = tid & 63;
  const int wid = tid >> 6;
  const int wr = wid >> 1, wc = wid & 1;
  const int m0 = blockIdx.x * 128;
  const int n0 = blockIdx.y * 128;
  const int g = lane >> 4, qc = lane & 15;

  float4 rA[8], rB[8];

#define PROJ_LOAD(ktof)                                                        \
  {                                                                            \
    _Pragma("unroll")                                                          \
    for (int i_ = 0; i_ < 4; i_++) {                                           \
      int gg_ = i_ * 256 + tid;                                                \
      int row_ = gg_ >> 3, c_ = gg_ & 7;                                       \
      const float4* pa_ = (const float4*)(A + (size_t)(m0 + row_) * FEA_ + (ktof) + c_ * 8); \
      rA[i_ * 2] = pa_[0]; rA[i_ * 2 + 1] = pa_[1];                            \
      const float4* pb_ = (const float4*)(W + (size_t)(n0 + row_) * FEA_ + (ktof) + c_ * 8); \
      rB[i_ * 2] = pb_[0]; rB[i_ * 2 + 1] = pb_[1];                            \
    }                                                                          \
  }

#define PROJ_WRITE(buf)                                                        \
  {                                                                            \
    _Pragma("unroll")                                                          \
    for (int i_ = 0; i_ < 4; i_++) {                                           \
      int gg_ = i_ * 256 + tid;                                                \
      int row_ = gg_ >> 3, c_ = gg_ & 7;                                       \
      bf16x8 av_;                                                              \
      av_[0] = f2bf(rA[i_ * 2].x);     av_[1] = f2bf(rA[i_ * 2].y);            \
      av_[2] = f2bf(rA[i_ * 2].z);     av_[3] = f2bf(rA[i_ * 2].w);            \
      av_[4] = f2bf(rA[i_ * 2 + 1].x); av_[5] = f2bf(rA[i_ * 2 + 1].y);        \
      av_[6] = f2bf(rA[i_ * 2 + 1].z); av_[7] = f2bf(rA[i_ * 2 + 1].w);        \
      *(bf16x8*)&lA[buf][row_ * 64 + ((c_ ^ (row_ & 7)) << 3)] = av_;          \
      bf16x8 bw_;                                                              \
      bw_[0] = f2bf(rB[i_ * 2].x);     bw_[1] = f2bf(rB[i_ * 2].y);            \
      bw_[2] = f2bf(rB[i_ * 2].z);     bw_[3] = f2bf(rB[i_ * 2].w);            \
      bw_[4] = f2bf(rB[i_ * 2 + 1].x); bw_[5] = f2bf(rB[i_ * 2 + 1].y);        \
      bw_[6] = f2bf(rB[i_ * 2 + 1].z); bw_[7] = f2bf(rB[i_ * 2 + 1].w);        \
      *(bf16x8*)&lB[buf][row_ * 64 + ((c_ ^ (row_ & 7)) << 3)] = bw_;          \
    }                                                                          \
  }

  f32x4 acc[4][4];
#pragma unroll
  for (int i = 0; i < 4; i++)
#pragma unroll
    for (int j = 0; j < 4; j++) acc[i][j] = f32x4{0.f, 0.f, 0.f, 0.f};

  PROJ_LOAD(0);
  PROJ_WRITE(0);
  __syncthreads();

  for (int kt = 0; kt < 12; kt++) {
    const int cur = kt & 1, nxt = cur ^ 1;
    if (kt < 11) PROJ_LOAD((kt + 1) * 64);
#pragma unroll
    for (int s = 0; s < 2; s++) {
      bf16x8 af[4], bfr[4];
#pragma unroll
      for (int i = 0; i < 4; i++) {
        int ar = wr * 64 + i * 16 + qc;
        af[i] = *(const bf16x8*)&lA[cur][ar * 64 + (((s * 4 + g) ^ (ar & 7)) << 3)];
        int br = wc * 64 + i * 16 + qc;
        bfr[i] = *(const bf16x8*)&lB[cur][br * 64 + (((s * 4 + g) ^ (br & 7)) << 3)];
      }
#pragma unroll
      for (int i = 0; i < 4; i++)
#pragma unroll
        for (int j = 0; j < 4; j++)
          acc[i][j] = __builtin_amdgcn_mfma_f32_16x16x32_bf16(af[i], bfr[j], acc[i][j], 0, 0, 0);
    }
    if (kt < 11) PROJ_WRITE(nxt);
    __syncthreads();
  }

  const int cn0 = n0 + wc * 64;
  float bv4[4];
#pragma unroll
  for (int j = 0; j < 4; j++) bv4[j] = bias[cn0 + j * 16 + qc];

#pragma unroll
  for (int i = 0; i < 4; i++) {
    int m = m0 + wr * 64 + i * 16 + g * 4;
    int bb = m >> 10;
    int l = m & 1023;
#pragma unroll
    for (int j = 0; j < 4; j++) {
      int n = cn0 + j * 16 + qc;
      int hh = n >> 6, d = n & 63;
#pragma unroll
      for (int r = 0; r < 4; r++) {
        unsigned short v = (unsigned short)f2bf(acc[i][j][r] + bv4[j]);
        if (which == 2) {
          Vt[(((size_t)bb * H_ + hh) * DK_ + d) * L_ + (l + r)] = v;
        } else if (which == 0) {
          Qb[(((size_t)bb * H_ + hh) * L_ + (l + r)) * DK_ + d] = v;
        } else {
          Kb[(((size_t)bb * H_ + hh) * L_ + (l + r)) * DK_ + d] = v;
        }
      }
    }
  }
#undef PROJ_LOAD
#undef PROJ_WRITE
}

// ---------------------------------------------------------------------------
// Fused attention v8: R4 memory schedule (depth-1 prefetch, vmcnt(12) counted
// barrier, 40KB LDS, 4 waves) + no-max softmax (register-only) + XCD-aware
// block mapping (block i -> XCD i&7; each XCD owns 6 (b,h) pairs x 16 q-tiles
// so K/V stay L2-resident per XCD). NORMAL scores stores (L2 write-merge;
// nt-store caused +67MB write amplification in R7).
// ---------------------------------------------------------------------------
__global__ __launch_bounds__(256, 3) void k_attn(
    const unsigned short* __restrict__ Qb, const unsigned short* __restrict__ Kb,
    const unsigned short* __restrict__ Vt,
    const float* __restrict__ preScores, const int* __restrict__ maskPAD,
    float* __restrict__ scoresOut, unsigned short* __restrict__ zp)
{
  __shared__ short lK[2][64 * 64];
  __shared__ short lV[2][64 * 64];
  __shared__ short lP[4][16 * 64];

  const int tid = threadIdx.x, lane = tid & 63, wid = tid >> 6;
  // XCD-aware decode: consecutive blockIdx round-robin across 8 XCDs.
  // XCD x gets bh in [x*6, x*6+6), all 16 q-tiles each. 768 = 8*6*16 exact.
  const int bi = blockIdx.x;
  const int slot = bi >> 3;                    // 0..95 within XCD
  const int bh_i = (bi & 7) * 6 + (slot >> 4); // 0..47
  const int qt = slot & 15;
  const int b = bh_i / H_;
  const int h = bh_i % H_;
  const int q0 = qt * 64;
  const int g = lane >> 4, qr = lane & 15;
  const int qrow = q0 + wid * 16 + qr;    // global q row in [0,1024)

  const size_t bh = (size_t)b * H_ + h;
  const unsigned short* __restrict__ Kbh = Kb + bh * L_ * DK_;
  const unsigned short* __restrict__ Vbh = Vt + bh * DK_ * L_;

  const int srow = lane >> 3;
  const int spos = lane & 7;

#define STAGE_KV(buf, kv0)                                                     \
  {                                                                            \
    _Pragma("unroll")                                                          \
    for (int i_ = 0; i_ < 2; i_++) {                                           \
      int r0_ = wid * 16 + i_ * 8;                                             \
      int row_ = r0_ + srow;                                                   \
      int cs_ = spos ^ (row_ & 7);                                             \
      __builtin_amdgcn_global_load_lds(                                        \
          (const __attribute__((address_space(1))) u32*)(Kbh +                 \
              (size_t)((kv0) + row_) * DK_ + cs_ * 8),                         \
          (__attribute__((address_space(3))) u32*)&lK[buf][r0_ * 64],          \
          16, 0, 0);                                                           \
      __builtin_amdgcn_global_load_lds(                                        \
          (const __attribute__((address_space(1))) u32*)(Vbh +                 \
              (size_t)row_ * L_ + (kv0) + cs_ * 8),                            \
          (__attribute__((address_space(3))) u32*)&lV[buf][r0_ * 64],          \
          16, 0, 0);                                                           \
    }                                                                          \
  }

  bf16x8 qf[2];
#pragma unroll
  for (int s = 0; s < 2; s++)
    qf[s] = *(const bf16x8*)(Qb + (bh * L_ + qrow) * DK_ + s * 32 + g * 8);

  f32x4 o[4];
#pragma unroll
  for (int i = 0; i < 4; i++) o[i] = f32x4{0.f, 0.f, 0.f, 0.f};
  float psum = 0.f;                       // per-lane partial sum (no-max)

  const size_t psBase = (bh * L_ + qrow) * L_;
  const size_t mkBase = ((size_t)b * L_ + qrow) * L_;

  // prologue: stage tile 0 (pinned oldest), prefetch ps/mask tile 0
  STAGE_KV(0, 0);
  __builtin_amdgcn_sched_barrier(0);
  float4 psn[4];
  int4 mkn[4];
#pragma unroll
  for (int i = 0; i < 4; i++) {
    psn[i] = *(const float4*)(preScores + psBase + i * 16 + g * 4);
    mkn[i] = *(const int4*)(maskPAD + mkBase + i * 16 + g * 4);
  }
  asm volatile("s_waitcnt vmcnt(8)" ::: "memory");
  __builtin_amdgcn_s_barrier();

  for (int kt = 0; kt < 16; kt++) {
    const int kv0 = kt * 64;
    const int cur = kt & 1, nxt = cur ^ 1;

    // issue next tile staging first; pin as oldest outstanding vmem
    if (kt < 15) {
      STAGE_KV(nxt, kv0 + 64);
    }
    __builtin_amdgcn_sched_barrier(0);

    // rotate ps/mask prefetch (depth-1, traffic-minimal)
    float4 psc[4]; int4 mkc[4];
#pragma unroll
    for (int i = 0; i < 4; i++) { psc[i] = psn[i]; mkc[i] = mkn[i]; }
    if (kt < 15) {
#pragma unroll
      for (int i = 0; i < 4; i++) {
        psn[i] = *(const float4*)(preScores + psBase + kv0 + 64 + i * 16 + g * 4);
        mkn[i] = *(const int4*)(maskPAD + mkBase + kv0 + 64 + i * 16 + g * 4);
      }
    }

    // S^T = K . Q^T from LDS
    f32x4 st[4];
#pragma unroll
    for (int i = 0; i < 4; i++) st[i] = f32x4{0.f, 0.f, 0.f, 0.f};
    __builtin_amdgcn_s_setprio(1);
#pragma unroll
    for (int s = 0; s < 2; s++) {
#pragma unroll
      for (int i = 0; i < 4; i++) {
        int kr = i * 16 + qr;
        bf16x8 kf = *(const bf16x8*)&lK[cur][kr * 64 + (((s * 4 + g) ^ (kr & 7)) << 3)];
        st[i] = __builtin_amdgcn_mfma_f32_16x16x32_bf16(kf, qf[s], st[i], 0, 0, 0);
      }
    }
    __builtin_amdgcn_s_setprio(0);

    // scale + preScores + mask; scores store (L2-merged); exp (no max);
    // pack P to wave-private LDS. No cross-lane ops in the loop.
#pragma unroll
    for (int i = 0; i < 4; i++) {
      int ko = i * 16 + g * 4;
      float4 sv;
      sv.x = (mkc[i].x == 0) ? MASKV : st[i][0] * 0.125f + psc[i].x;
      sv.y = (mkc[i].y == 0) ? MASKV : st[i][1] * 0.125f + psc[i].y;
      sv.z = (mkc[i].z == 0) ? MASKV : st[i][2] * 0.125f + psc[i].z;
      sv.w = (mkc[i].w == 0) ? MASKV : st[i][3] * 0.125f + psc[i].w;
      *(float4*)(scoresOut + psBase + kv0 + ko) = sv;
      float p0 = __expf(sv.x);
      float p1 = __expf(sv.y);
      float p2 = __expf(sv.z);
      float p3 = __expf(sv.w);
      psum += (p0 + p1) + (p2 + p3);
      s16x4 pw = {f2bf(p0), f2bf(p1), f2bf(p2), f2bf(p3)};
      int c = i * 2 + (g >> 1);
      *(s16x4*)&lP[wid][qr * 64 + ((c ^ (qr & 7)) << 3) + ((g & 1) << 2)] = pw;
    }

    // O^T += Vt_strip . P^T from LDS
    __builtin_amdgcn_s_setprio(1);
#pragma unroll
    for (int s = 0; s < 2; s++) {
      bf16x8 pf = *(const bf16x8*)&lP[wid][qr * 64 + (((s * 4 + g) ^ (qr & 7)) << 3)];
#pragma unroll
      for (int i = 0; i < 4; i++) {
        int vr = i * 16 + qr;
        bf16x8 vf = *(const bf16x8*)&lV[cur][vr * 64 + (((s * 4 + g) ^ (vr & 7)) << 3)];
        o[i] = __builtin_amdgcn_mfma_f32_16x16x32_bf16(vf, pf, o[i], 0, 0, 0);
      }
    }
    __builtin_amdgcn_s_setprio(0);

    // counted barrier: wait only the 4 staging loads (oldest); scores stores
    // (4) and ps/mask prefetch (8) stay in flight.
    asm volatile("s_waitcnt vmcnt(12)" ::: "memory");
    __builtin_amdgcn_s_barrier();
  }

  // final row-sum reduce (2 shuffles) + normalize + write z_pre
  psum += __shfl_xor(psum, 16);
  psum += __shfl_xor(psum, 32);
  float inv = 1.f / psum;
  size_t zr = ((size_t)b * L_ + qrow) * FEA_ + (size_t)h * DK_;
#pragma unroll
  for (int i = 0; i < 4; i++) {
    s16x4 zw = {f2bf(o[i][0] * inv), f2bf(o[i][1] * inv),
                f2bf(o[i][2] * inv), f2bf(o[i][3] * inv)};
    *(s16x4*)((unsigned short*)zp + zr + i * 16 + g * 4) = zw;
  }
#undef STAGE_KV
}

// ---------------------------------------------------------------------------
// Output projection: out[m][n] = sum_k zp[m][k] * Wo[n][k] + bo[n], fp32 out.
// Double-buffered LDS, 1 barrier/k-step, loads issued before compute.
// ---------------------------------------------------------------------------
__global__ __launch_bounds__(256) void k_oproj(
    const unsigned short* __restrict__ zp,
    const float* __restrict__ Wo, const float* __restrict__ bo,
    float* __restrict__ out)
{
  __shared__ short lA[2][128 * 64];
  __shared__ short lB[2][128 * 64];

  const int tid = threadIdx.x;
  const int lane = tid & 63;
  const int wid = tid >> 6;
  const int wr = wid >> 1, wc = wid & 1;
  const int m0 = blockIdx.x * 128;
  const int n0 = blockIdx.y * 128;
  const int g = lane >> 4, qc = lane & 15;

  bf16x8 rA[4];
  float4 rB[8];

#define OP_LOAD(ktof)                                                          \
  {                                                                            \
    _Pragma("unroll")                                                          \
    for (int i_ = 0; i_ < 4; i_++) {                                           \
      int gg_ = i_ * 256 + tid;                                                \
      int row_ = gg_ >> 3, c_ = gg_ & 7;                                       \
      rA[i_] = *(const bf16x8*)(zp + (size_t)(m0 + row_) * FEA_ + (ktof) + c_ * 8); \
      const float4* pb_ = (const float4*)(Wo + (size_t)(n0 + row_) * FEA_ + (ktof) + c_ * 8); \
      rB[i_ * 2] = pb_[0]; rB[i_ * 2 + 1] = pb_[1];                            \
    }                                                                          \
  }

#define OP_WRITE(buf)                                                          \
  {                                                                            \
    _Pragma("unroll")                                                          \
    for (int i_ = 0; i_ < 4; i_++) {                                           \
      int gg_ = i_ * 256 + tid;                                                \
      int row_ = gg_ >> 3, c_ = gg_ & 7;                                       \
      *(bf16x8*)&lA[buf][row_ * 64 + ((c_ ^ (row_ & 7)) << 3)] = rA[i_];       \
      bf16x8 bw_;                                                              \
      bw_[0] = f2bf(rB[i_ * 2].x);     bw_[1] = f2bf(rB[i_ * 2].y);            \
      bw_[2] = f2bf(rB[i_ * 2].z);     bw_[3] = f2bf(rB[i_ * 2].w);            \
      bw_[4] = f2bf(rB[i_ * 2 + 1].x); bw_[5] = f2bf(rB[i_ * 2 + 1].y);        \
      bw_[6] = f2bf(rB[i_ * 2 + 1].z); bw_[7] = f2bf(rB[i_ * 2 + 1].w);        \
      *(bf16x8*)&lB[buf][row_ * 64 + ((c_ ^ (row_ & 7)) << 3)] = bw_;          \
    }                                                                          \
  }

  f32x4 acc[4][4];
#pragma unroll
  for (int i = 0; i < 4; i++)
#pragma unroll
    for (int j = 0; j < 4; j++) acc[i][j] = f32x4{0.f, 0.f, 0.f, 0.f};

  OP_LOAD(0);
  OP_WRITE(0);
  __syncthreads();

  for (int kt = 0; kt < 12; kt++) {
    const int cur = kt & 1, nxt = cur ^ 1;
    if (kt < 11) OP_LOAD((kt + 1) * 64);
#pragma unroll
    for (int s = 0; s < 2; s++) {
      bf16x8 af[4], bfr[4];
#pragma unroll
      for (int i = 0; i < 4; i++) {
        int ar = wr * 64 + i * 16 + qc;
        af[i] = *(const bf16x8*)&lA[cur][ar * 64 + (((s * 4 + g) ^ (ar & 7)) << 3)];
        int br = wc * 64 + i * 16 + qc;
        bfr[i] = *(const bf16x8*)&lB[cur][br * 64 + (((s * 4 + g) ^ (br & 7)) << 3)];
      }
#pragma unroll
      for (int i = 0; i < 4; i++)
#pragma unroll
        for (int j = 0; j < 4; j++)
          acc[i][j] = __builtin_amdgcn_mfma_f32_16x16x32_bf16(af[i], bfr[j], acc[i][j], 0, 0, 0);
    }
    if (kt < 11) OP_WRITE(nxt);
    __syncthreads();
  }

  const int cn0 = n0 + wc * 64;
  float bv4[4];
#pragma unroll
  for (int j = 0; j < 4; j++) bv4[j] = bo[cn0 + j * 16 + qc];

#pragma unroll
  for (int i = 0; i < 4; i++) {
    int m = m0 + wr * 64 + i * 16 + g * 4;
#pragma unroll
    for (int j = 0; j < 4; j++) {
      int n = cn0 + j * 16 + qc;
#pragma unroll
      for (int r = 0; r < 4; r++) {
        out[(size_t)(m + r) * FEA_ + n] = acc[i][j][r] + bv4[j];
      }
    }
  }
#undef OP_LOAD
#undef OP_WRITE
}

extern "C" void kernel_launch(void* const* d_in, const int* in_sizes, int n_in,
                              void* d_out, int out_size, void* d_ws, size_t ws_size,
                              hipStream_t stream) {
  const float* qx = (const float*)d_in[0];
  const float* kx = (const float*)d_in[1];
  const float* vx = (const float*)d_in[2];
  const float* preScores = (const float*)d_in[3];
  const int* maskPAD = (const int*)d_in[4];
  const float* Wq = (const float*)d_in[5];
  const float* bq = (const float*)d_in[6];
  const float* Wk = (const float*)d_in[7];
  const float* bk = (const float*)d_in[8];
  const float* Wv = (const float*)d_in[9];
  const float* bv = (const float*)d_in[10];
  const float* Wo = (const float*)d_in[11];
  const float* bo = (const float*)d_in[12];

  float* z_out = (float*)d_out;
  float* scores_out = z_out + (size_t)B_ * L_ * FEA_;

  unsigned short* Qb = (unsigned short*)d_ws;
  unsigned short* Kb = Qb + (size_t)B_ * H_ * L_ * DK_;
  unsigned short* Vt = Kb + (size_t)B_ * H_ * L_ * DK_;
  unsigned short* zp = Vt + (size_t)B_ * H_ * L_ * DK_;

  k_proj<<<dim3(32, 6, 3), 256, 0, stream>>>(qx, kx, vx, Wq, bq, Wk, bk, Wv, bv,
                                             Qb, Kb, Vt);
  k_attn<<<dim3(8 * 6 * 16, 1, 1), 256, 0, stream>>>(Qb, Kb, Vt, preScores,
                                                     maskPAD, scores_out, zp);
  k_oproj<<<dim3(32, 6, 1), 256, 0, stream>>>(zp, Wo, bo, z_out);
}